// Round 3
// 811.212 us; speedup vs baseline: 1.0282x; 1.0282x over previous
//
#include <hip/hip_runtime.h>

// Row-wise sparsemax over 4096 x 32000 fp32.
// One block (1024 threads) per row; row lives in registers (8 float4/thread).
// tau found via candidate-set Michelot: support subset of {x > rowmax - 1}.
//
// R2 = R1 with compile fix: __builtin_nontemporal_* requires native clang
// vector types, not HIP_vector_type<float,4>. Use ext_vector_type(4) for the
// memory ops (same global_load/store_dwordx4), shuffle to float4 in regs.
//
// R1 change vs 834us baseline:
//  - __launch_bounds__(1024, 4): (1024, 8) capped the allocator at 64 VGPRs
//    while ~32 VGPRs are the register-resident row alone -> spill theory for
//    the 5x gap to memory roofline. 128-VGPR cap guarantees no spill; 1
//    block/CU still has ~128KB of loads in flight per CU.
//  - non-temporal load/store: row is read once, output never re-read; L2
//    residency is pure pollution.

#define NCOL 32000
#define NV4  8000          // NCOL / 4
#define NT   1024
#define VPT  8             // float4 per thread (1024*8 = 8192 >= 8000)
#define CAP  1024          // candidate list capacity (== NT so init is 1 store/thread)

typedef float v4f __attribute__((ext_vector_type(4)));

__global__ __launch_bounds__(NT, 4)
void sparsemax_kernel(const float* __restrict__ x, float* __restrict__ out) {
    __shared__ float sred[16];
    __shared__ float sS[16];
    __shared__ int   sK[16];
    __shared__ float scand[CAP];
    __shared__ int   scnt;

    const int tid  = threadIdx.x;
    const int lane = tid & 63;
    const int wave = tid >> 6;
    const long long row = blockIdx.x;

    const v4f* __restrict__ xr   = (const v4f*)(x + row * NCOL);
    v4f* __restrict__       outr = (v4f*)(out + row * NCOL);

    // ---- load row into registers (coalesced float4, read-once -> nt) ----
    float4 v[VPT];
#pragma unroll
    for (int j = 0; j < VPT; ++j) {
        const int q = tid + j * NT;
        if (j < VPT - 1 || q < NV4) {
            const v4f t = __builtin_nontemporal_load(&xr[q]);
            v[j] = make_float4(t.x, t.y, t.z, t.w);
        } else {
            v[j] = make_float4(-1e30f, -1e30f, -1e30f, -1e30f);
        }
    }

    // init LDS (before barrier 1)
    scand[tid] = -1e30f;           // CAP == NT
    if (tid == 0) scnt = 0;

    // ---- phase 1: row max ----
    float m = -1e30f;
#pragma unroll
    for (int j = 0; j < VPT; ++j)
        m = fmaxf(m, fmaxf(fmaxf(v[j].x, v[j].y), fmaxf(v[j].z, v[j].w)));
#pragma unroll
    for (int off = 32; off > 0; off >>= 1)
        m = fmaxf(m, __shfl_down(m, off, 64));
    if (lane == 0) sred[wave] = m;
    __syncthreads();
    float M = sred[0];
#pragma unroll
    for (int w = 1; w < 16; ++w) M = fmaxf(M, sred[w]);
    const float thr = M - 1.0f;    // tau* >= M - 1, so support ⊆ {z > thr}

    // ---- phase 2: gather candidates > thr into LDS ----
#pragma unroll
    for (int j = 0; j < VPT; ++j) {
        const float e0 = v[j].x, e1 = v[j].y, e2 = v[j].z, e3 = v[j].w;
        if (e0 > thr) { int p = atomicAdd(&scnt, 1); if (p < CAP) scand[p] = e0; }
        if (e1 > thr) { int p = atomicAdd(&scnt, 1); if (p < CAP) scand[p] = e1; }
        if (e2 > thr) { int p = atomicAdd(&scnt, 1); if (p < CAP) scand[p] = e2; }
        if (e3 > thr) { int p = atomicAdd(&scnt, 1); if (p < CAP) scand[p] = e3; }
    }
    __syncthreads();
    const int cnt = scnt;

    // ---- phase 3: solve for tau (Michelot, exact finite convergence) ----
    float tau;
    if (cnt <= CAP) {
        // every wave solves redundantly from the LDS list (no extra barrier)
        float tau_l = thr;
        int kprev = -1;
        if (cnt <= 64) {
            const float cv = scand[lane];   // padded with -1e30
            for (int it = 0; it < 130; ++it) {
                float Sl = (cv > tau_l) ? cv : 0.0f;
                int   kl = (cv > tau_l) ? 1 : 0;
#pragma unroll
                for (int off = 32; off > 0; off >>= 1) {
                    Sl += __shfl_down(Sl, off, 64);
                    kl += __shfl_down(kl, off, 64);
                }
                const float St = __shfl(Sl, 0, 64);
                const int   kt = __shfl(kl, 0, 64);
                tau_l = (St - 1.0f) / (float)kt;
                if (kt == kprev) break;
                kprev = kt;
            }
        } else {
            const int cr = (cnt + 63) & ~63;   // padded region is -1e30
            for (int it = 0; it < CAP + 2; ++it) {
                float Sl = 0.0f; int kl = 0;
                for (int p = lane; p < cr; p += 64) {
                    const float e = scand[p];
                    if (e > tau_l) { Sl += e; kl++; }
                }
#pragma unroll
                for (int off = 32; off > 0; off >>= 1) {
                    Sl += __shfl_down(Sl, off, 64);
                    kl += __shfl_down(kl, off, 64);
                }
                const float St = __shfl(Sl, 0, 64);
                const int   kt = __shfl(kl, 0, 64);
                tau_l = (St - 1.0f) / (float)kt;
                if (kt == kprev) break;
                kprev = kt;
            }
        }
        tau = tau_l;
    } else {
        // fallback (pathological inputs): full-register Michelot, block reductions
        float tau_l = thr;
        int kprev = -1;
        for (int it = 0; it < 300; ++it) {
            float Sl = 0.0f; int kl = 0;
#pragma unroll
            for (int j = 0; j < VPT; ++j) {
                const float e0 = v[j].x, e1 = v[j].y, e2 = v[j].z, e3 = v[j].w;
                if (e0 > tau_l) { Sl += e0; kl++; }
                if (e1 > tau_l) { Sl += e1; kl++; }
                if (e2 > tau_l) { Sl += e2; kl++; }
                if (e3 > tau_l) { Sl += e3; kl++; }
            }
#pragma unroll
            for (int off = 32; off > 0; off >>= 1) {
                Sl += __shfl_down(Sl, off, 64);
                kl += __shfl_down(kl, off, 64);
            }
            if (lane == 0) { sS[wave] = Sl; sK[wave] = kl; }
            __syncthreads();
            float St = 0.0f; int kt = 0;
#pragma unroll
            for (int w = 0; w < 16; ++w) { St += sS[w]; kt += sK[w]; }
            const float tnew = (St - 1.0f) / (float)kt;
            __syncthreads();               // protect sS/sK reuse next iter
            tau_l = tnew;
            if (kt == kprev) break;
            kprev = kt;
        }
        tau = tau_l;
    }

    // ---- phase 4: write output (never re-read -> nt stores) ----
#pragma unroll
    for (int j = 0; j < VPT; ++j) {
        const int q = tid + j * NT;
        if (j < VPT - 1 || q < NV4) {
            v4f o;
            o.x = fmaxf(v[j].x - tau, 0.0f);
            o.y = fmaxf(v[j].y - tau, 0.0f);
            o.z = fmaxf(v[j].z - tau, 0.0f);
            o.w = fmaxf(v[j].w - tau, 0.0f);
            __builtin_nontemporal_store(o, &outr[q]);
        }
    }
}

extern "C" void kernel_launch(void* const* d_in, const int* in_sizes, int n_in,
                              void* d_out, int out_size, void* d_ws, size_t ws_size,
                              hipStream_t stream) {
    const float* x = (const float*)d_in[0];
    float* out = (float*)d_out;
    const int rows = in_sizes[0] / NCOL;   // 4096
    sparsemax_kernel<<<rows, NT, 0, stream>>>(x, out);
}

// Round 4
// 800.692 us; speedup vs baseline: 1.0417x; 1.0131x over previous
//
#include <hip/hip_runtime.h>

// Row-wise sparsemax over 4096 x 32000 fp32.
// One block per row; row lives in registers; tau via candidate-set Michelot
// (support subset of {x > rowmax - 1}).
//
// R3 change vs R2 (811us measured, kernel dispatch itself <328us per rocprof):
//  - 512 threads/block, VPT=16 (was 1024/8). Row still register-resident
//    (64 data VGPRs, ~100 total), but now __launch_bounds__(512,4) fits
//    TWO blocks per CU (16 waves, 128-VGPR cap). Block A's serial phases
//    (barrier reduce + Michelot solve, ~3-6us/row) overlap block B's
//    HBM streaming -> memory pipe never idles. Same one-pass traffic
//    floor: 1.05 GB = 166us @ 6.3 TB/s.
//  - R2's nt load/store kept (row read once, output never re-read).

#define NCOL  32000
#define NV4   8000         // NCOL / 4
#define NT    512
#define VPT   16           // float4 per thread (512*16 = 8192 >= 8000)
#define NWAVE 8            // NT / 64
#define CAP   1024         // candidate list capacity

typedef float v4f __attribute__((ext_vector_type(4)));

__global__ __launch_bounds__(NT, 4)
void sparsemax_kernel(const float* __restrict__ x, float* __restrict__ out) {
    __shared__ float sred[NWAVE];
    __shared__ float sS[NWAVE];
    __shared__ int   sK[NWAVE];
    __shared__ float scand[CAP];
    __shared__ int   scnt;

    const int tid  = threadIdx.x;
    const int lane = tid & 63;
    const int wave = tid >> 6;
    const long long row = blockIdx.x;

    const v4f* __restrict__ xr   = (const v4f*)(x + row * NCOL);
    v4f* __restrict__       outr = (v4f*)(out + row * NCOL);

    // ---- load row into registers (coalesced float4, read-once -> nt) ----
    float4 v[VPT];
#pragma unroll
    for (int j = 0; j < VPT; ++j) {
        const int q = tid + j * NT;
        if (j < VPT - 1 || q < NV4) {
            const v4f t = __builtin_nontemporal_load(&xr[q]);
            v[j] = make_float4(t.x, t.y, t.z, t.w);
        } else {
            v[j] = make_float4(-1e30f, -1e30f, -1e30f, -1e30f);
        }
    }

    // init LDS (before barrier 1); CAP == 2*NT
    scand[tid]      = -1e30f;
    scand[tid + NT] = -1e30f;
    if (tid == 0) scnt = 0;

    // ---- phase 1: row max ----
    float m = -1e30f;
#pragma unroll
    for (int j = 0; j < VPT; ++j)
        m = fmaxf(m, fmaxf(fmaxf(v[j].x, v[j].y), fmaxf(v[j].z, v[j].w)));
#pragma unroll
    for (int off = 32; off > 0; off >>= 1)
        m = fmaxf(m, __shfl_down(m, off, 64));
    if (lane == 0) sred[wave] = m;
    __syncthreads();
    float M = sred[0];
#pragma unroll
    for (int w = 1; w < NWAVE; ++w) M = fmaxf(M, sred[w]);
    const float thr = M - 1.0f;    // tau* >= M - 1, so support ⊆ {z > thr}

    // ---- phase 2: gather candidates > thr into LDS ----
#pragma unroll
    for (int j = 0; j < VPT; ++j) {
        const float e0 = v[j].x, e1 = v[j].y, e2 = v[j].z, e3 = v[j].w;
        if (e0 > thr) { int p = atomicAdd(&scnt, 1); if (p < CAP) scand[p] = e0; }
        if (e1 > thr) { int p = atomicAdd(&scnt, 1); if (p < CAP) scand[p] = e1; }
        if (e2 > thr) { int p = atomicAdd(&scnt, 1); if (p < CAP) scand[p] = e2; }
        if (e3 > thr) { int p = atomicAdd(&scnt, 1); if (p < CAP) scand[p] = e3; }
    }
    __syncthreads();
    const int cnt = scnt;

    // ---- phase 3: solve for tau (Michelot, exact finite convergence) ----
    float tau;
    if (cnt <= CAP) {
        // every wave solves redundantly from the LDS list (no extra barrier)
        float tau_l = thr;
        int kprev = -1;
        if (cnt <= 64) {
            const float cv = scand[lane];   // padded with -1e30
            for (int it = 0; it < 130; ++it) {
                float Sl = (cv > tau_l) ? cv : 0.0f;
                int   kl = (cv > tau_l) ? 1 : 0;
#pragma unroll
                for (int off = 32; off > 0; off >>= 1) {
                    Sl += __shfl_down(Sl, off, 64);
                    kl += __shfl_down(kl, off, 64);
                }
                const float St = __shfl(Sl, 0, 64);
                const int   kt = __shfl(kl, 0, 64);
                tau_l = (St - 1.0f) / (float)kt;
                if (kt == kprev) break;
                kprev = kt;
            }
        } else {
            const int cr = (cnt + 63) & ~63;   // padded region is -1e30
            for (int it = 0; it < CAP + 2; ++it) {
                float Sl = 0.0f; int kl = 0;
                for (int p = lane; p < cr; p += 64) {
                    const float e = scand[p];
                    if (e > tau_l) { Sl += e; kl++; }
                }
#pragma unroll
                for (int off = 32; off > 0; off >>= 1) {
                    Sl += __shfl_down(Sl, off, 64);
                    kl += __shfl_down(kl, off, 64);
                }
                const float St = __shfl(Sl, 0, 64);
                const int   kt = __shfl(kl, 0, 64);
                tau_l = (St - 1.0f) / (float)kt;
                if (kt == kprev) break;
                kprev = kt;
            }
        }
        tau = tau_l;
    } else {
        // fallback (pathological inputs): full-register Michelot, block reductions
        float tau_l = thr;
        int kprev = -1;
        for (int it = 0; it < 300; ++it) {
            float Sl = 0.0f; int kl = 0;
#pragma unroll
            for (int j = 0; j < VPT; ++j) {
                const float e0 = v[j].x, e1 = v[j].y, e2 = v[j].z, e3 = v[j].w;
                if (e0 > tau_l) { Sl += e0; kl++; }
                if (e1 > tau_l) { Sl += e1; kl++; }
                if (e2 > tau_l) { Sl += e2; kl++; }
                if (e3 > tau_l) { Sl += e3; kl++; }
            }
#pragma unroll
            for (int off = 32; off > 0; off >>= 1) {
                Sl += __shfl_down(Sl, off, 64);
                kl += __shfl_down(kl, off, 64);
            }
            if (lane == 0) { sS[wave] = Sl; sK[wave] = kl; }
            __syncthreads();
            float St = 0.0f; int kt = 0;
#pragma unroll
            for (int w = 0; w < NWAVE; ++w) { St += sS[w]; kt += sK[w]; }
            const float tnew = (St - 1.0f) / (float)kt;
            __syncthreads();               // protect sS/sK reuse next iter
            tau_l = tnew;
            if (kt == kprev) break;
            kprev = kt;
        }
        tau = tau_l;
    }

    // ---- phase 4: write output (never re-read -> nt stores) ----
#pragma unroll
    for (int j = 0; j < VPT; ++j) {
        const int q = tid + j * NT;
        if (j < VPT - 1 || q < NV4) {
            v4f o;
            o.x = fmaxf(v[j].x - tau, 0.0f);
            o.y = fmaxf(v[j].y - tau, 0.0f);
            o.z = fmaxf(v[j].z - tau, 0.0f);
            o.w = fmaxf(v[j].w - tau, 0.0f);
            __builtin_nontemporal_store(o, &outr[q]);
        }
    }
}

extern "C" void kernel_launch(void* const* d_in, const int* in_sizes, int n_in,
                              void* d_out, int out_size, void* d_ws, size_t ws_size,
                              hipStream_t stream) {
    const float* x = (const float*)d_in[0];
    float* out = (float*)d_out;
    const int rows = in_sizes[0] / NCOL;   // 4096
    sparsemax_kernel<<<rows, NT, 0, stream>>>(x, out);
}